// Round 9
// baseline (536.155 us; speedup 1.0000x reference)
//
#include <hip/hip_runtime.h>
#include <math.h>

#define N_ATOMS 16384
#define APC 64
#define N_CONF 256
#define N_MOL 64
#define DEG 32
#define NEDGE (N_ATOMS * DEG)
#define H 128
#define G 50
#define NL 6
#define TP0 512          // fp32 source table points
#define TPB 4096         // bf16 nearest table points
#define CUTOFF 10.0f

typedef __attribute__((ext_vector_type(8))) short short8_t;
typedef __attribute__((ext_vector_type(4))) float f32x4;
typedef __attribute__((ext_vector_type(2))) float f32x2;

__device__ __forceinline__ float ssp_f(float x) {
  float e = __expf(-fabsf(x));
  return fmaxf(x, 0.f) + __logf(1.f + e) - 0.69314718055994531f;
}
__device__ __forceinline__ unsigned short bf16_rne(float x) {
  unsigned u = __float_as_uint(x);
  unsigned r = u + 0x7FFF + ((u >> 16) & 1);
  return (unsigned short)(r >> 16);
}
__device__ __forceinline__ float bf16_to_f(unsigned short s) {
  return __uint_as_float(((unsigned)s) << 16);
}
__device__ __forceinline__ float bflo(unsigned u) { return __uint_as_float(u << 16); }
__device__ __forceinline__ float bfhi(unsigned u) { return __uint_as_float(u & 0xFFFF0000u); }

#define MFMA(a, b, c) __builtin_amdgcn_mfma_f32_16x16x32_bf16((a), (b), (c), 0, 0, 0)

// wave handles 2 row-tiles (rt2 half) x 1 col-tile nt; B loaded once per kb.
__device__ __forceinline__ void gemm_rt2(const short (*AH)[136], const short (*AL)[136],
                                         const short* __restrict__ pw,
                                         int rt2, int nt, int lane, int quad, int ln,
                                         f32x4 acc[2]) {
  #pragma unroll
  for (int kb = 0; kb < 4; kb++) {
    const short* pb = pw + ((size_t)(kb * 8 + nt) * 64 + lane) * 8;
    short8_t bh = *(const short8_t*)pb;
    short8_t bl = *(const short8_t*)(pb + 16384);
    int ko = kb * 32 + quad * 8;
    #pragma unroll
    for (int rtt = 0; rtt < 2; rtt++) {
      int row = rt2 * 32 + rtt * 16 + ln;
      short8_t ah = *(const short8_t*)&AH[row][ko];
      short8_t al = *(const short8_t*)&AL[row][ko];
      acc[rtt] = MFMA(ah, bh, acc[rtt]);
      acc[rtt] = MFMA(ah, bl, acc[rtt]);
      acc[rtt] = MFMA(al, bh, acc[rtt]);
    }
  }
}

// Single persistent kernel: setup (table/weights) + grid barriers + per-conformer
// network + fused mol pool/head.  grid = 256 blocks x 1024 thr, 1 block/CU.
__global__ __launch_bounds__(1024, 1) void k_all(
    const int* __restrict__ z, const float* __restrict__ pos,
    const int* __restrict__ esrc, const float* __restrict__ emb,
    const float* __restrict__ mlp_w1, const float* __restrict__ mlp_b1,
    const float* __restrict__ mlp_w2, const float* __restrict__ mlp_b2,
    const float* __restrict__ cf_w1, const float* __restrict__ cf_w2,
    const float* __restrict__ cf_b2, const float* __restrict__ int_w,
    const float* __restrict__ int_b, const float* __restrict__ out_w1,
    const float* __restrict__ out_b1, const float* __restrict__ out_w2,
    const float* __restrict__ out_b2, const float* __restrict__ hw1,
    const float* __restrict__ hb1, const float* __restrict__ hw2,
    const float* __restrict__ hb2, float* __restrict__ T,
    unsigned short* __restrict__ Tb, short* __restrict__ PW,
    float* __restrict__ ce, int* __restrict__ cnt, float* __restrict__ outp) {
  __shared__ __align__(16) char smem[148240];
  float (*xs)[132] = (float (*)[132])(smem);                    // 33792
  short (*hH)[136] = (short (*)[136])(smem + 33792);            // 17408
  short (*hL)[136] = (short (*)[136])(smem + 51200);
  short (*tH)[136] = (short (*)[136])(smem + 68608);
  short (*tL)[136] = (short (*)[136])(smem + 86016);
  short (*S1H)[136] = (short (*)[136])(smem + 103424);
  short (*S1L)[136] = (short (*)[136])(smem + 120832);
  int* pks = (int*)(smem + 138240);                             // 2048 ints
  float (*ps)[128] = (float (*)[128])(smem + 146432);           // 2x128
  float* posL = (float*)(smem + 147456);                        // 192 floats
  int* is_last = (int*)(smem + 148224);

  const int b = blockIdx.x;
  const int tid = threadIdx.x;

  // ================= Phase A: weight swizzle + fp32 table =================
  // PW: 40960 fragment tasks, 160 per block
  if (tid < 160) {
    int e = b * 160 + tid;
    int g = e >> 11, t = e & 2047;
    int kb = t >> 9, rem = t & 511, nt = rem >> 6, lane = rem & 63;
    int quad = lane >> 4, ln = lane & 15;
    int kbase = kb * 32 + quad * 8;
    int n = nt * 16 + ln;
    const float* src;
    if (g < 12) {
      int l = g >> 1;
      src = (g & 1) ? (int_w + l * 16384) : (cf_w2 + l * 16384);
    } else if (g < 18) {
      src = cf_w1 + (g - 12) * 16384;
    } else {
      src = (g == 18) ? out_w1 : out_w2;
    }
    short hv[8], lv[8];
    #pragma unroll
    for (int j = 0; j < 8; j++) {
      float x = src[(kbase + j) * H + n];
      unsigned short hb = bf16_rne(x);
      hv[j] = (short)hb;
      lv[j] = (short)bf16_rne(x - bf16_to_f(hb));
    }
    size_t base = (size_t)g * 32768 + (size_t)t * 8;
    *(short8_t*)&PW[base] = *(short8_t*)hv;
    *(short8_t*)&PW[base + 16384] = *(short8_t*)lv;
  }
  // fp32 table: 3072 points total, 12 per block (2 rounds x 8 groups)
  {
    float* g8 = (float*)smem;             // [8][64]
    float* S8 = (float*)(smem + 2048);    // [8][128]
    const float gspace = CUTOFF / (float)(G - 1);
    const float coeff = -0.5f / (gspace * gspace);
    const int grp = tid >> 7, c = tid & 127;
    for (int r = 0; r < 2; r++) {
      int pl = r * 8 + grp;
      bool act = (pl < 12);
      int pidx = b * 12 + (pl < 12 ? pl : 0);
      int l = pidx >> 9, p = pidx & 511;
      float d = (float)p * (CUTOFF / (float)(TP0 - 1));
      if (act && c < G) {
        float x = d - (float)c * gspace;
        g8[grp * 64 + c] = __expf(coeff * x * x);
      }
      __syncthreads();
      if (act) {
        const float* W1 = mlp_w1 + l * G * H;
        float s = mlp_b1[l * H + c];
        #pragma unroll 5
        for (int i = 0; i < G; i++) s += g8[grp * 64 + i] * W1[i * H + c];
        S8[grp * 128 + c] = ssp_f(s);
      }
      __syncthreads();
      if (act) {
        const float* W2 = mlp_w2 + l * H * H;
        float o = mlp_b2[l * H + c];
        #pragma unroll 8
        for (int j = 0; j < H; j++) o += S8[grp * 128 + j] * W2[j * H + c];
        float Cc = 0.5f * (__cosf(d * (3.14159265358979f / CUTOFF)) + 1.f);
        T[((size_t)l * TP0 + p) * H + c] = o * Cc;
      }
      __syncthreads();
    }
  }
  // ---- grid barrier 1 ----
  __threadfence();
  __syncthreads();
  if (tid == 0) {
    __hip_atomic_fetch_add(&cnt[0], 1, __ATOMIC_ACQ_REL, __HIP_MEMORY_SCOPE_AGENT);
    while (__hip_atomic_load(&cnt[0], __ATOMIC_ACQUIRE, __HIP_MEMORY_SCOPE_AGENT)
           != N_CONF)
      __builtin_amdgcn_s_sleep(32);
  }
  __syncthreads();
  __threadfence();

  // ================= Phase B: upsample to bf16 TPB table =================
  {
    int gt = b * 1024 + tid;
    #pragma unroll
    for (int k = 0; k < 3; k++) {
      int t = gt + k * 262144;              // < NL*TPB*H/4 = 786432
      int l = t >> 17;                      // TPB*H/4 = 131072
      int rem = t & 131071;
      int p4 = rem >> 5, cg = rem & 31;
      int c = cg * 4;
      float u = (float)p4 * ((float)(TP0 - 1) / (float)(TPB - 1));
      int i = (int)u;
      if (i > TP0 - 2) i = TP0 - 2;
      float f = u - (float)i;
      const float* a = T + ((size_t)l * TP0 + i) * H + c;
      float4 v0 = *(const float4*)a;
      float4 v1 = *(const float4*)(a + H);
      ushort4 o;
      o.x = bf16_rne(v0.x + f * (v1.x - v0.x));
      o.y = bf16_rne(v0.y + f * (v1.y - v0.y));
      o.z = bf16_rne(v0.z + f * (v1.z - v0.z));
      o.w = bf16_rne(v0.w + f * (v1.w - v0.w));
      *(ushort4*)&Tb[((size_t)l * TPB + p4) * H + c] = o;
    }
  }
  // ---- grid barrier 2 ----
  __threadfence();
  __syncthreads();
  if (tid == 0) {
    __hip_atomic_fetch_add(&cnt[1], 1, __ATOMIC_ACQ_REL, __HIP_MEMORY_SCOPE_AGENT);
    while (__hip_atomic_load(&cnt[1], __ATOMIC_ACQUIRE, __HIP_MEMORY_SCOPE_AGENT)
           != N_CONF)
      __builtin_amdgcn_s_sleep(32);
  }
  __syncthreads();
  __threadfence();

  // ================= Phase C: per-conformer network =================
  const int conf = b;
  const int lane = tid & 63, w = tid >> 6;       // 16 waves
  const int quad = lane >> 4, ln = lane & 15;
  const int rt2 = w & 1, nt = w >> 1;            // 2 row-halves x 8 col-tiles
  const int eg = lane >> 4, ch0 = (lane & 15) * 8;

  // stage conformer positions
  if (tid < 192) posL[tid] = pos[conf * 192 + tid];
  __syncthreads();
  // local edge records: distance -> (table byte offset | src_local<<20)
  #pragma unroll
  for (int k = 0; k < 2; k++) {
    int e2 = k * 1024 + tid;
    int r = esrc[conf * 2048 + e2];
    int rl = r & (APC - 1);
    int ca = e2 >> 5;
    float dx = posL[rl * 3 + 0] - posL[ca * 3 + 0];
    float dy = posL[rl * 3 + 1] - posL[ca * 3 + 1];
    float dz = posL[rl * 3 + 2] - posL[ca * 3 + 2];
    float d = sqrtf(dx * dx + dy * dy + dz * dz);
    int i = (int)(d * ((float)(TPB - 1) / CUTOFF) + 0.5f);
    if (i > TPB - 1) i = TPB - 1;
    if (i < 0) i = 0;
    pks[e2] = (i << 8) | (rl << 20);
  }
  // init h from emb
  {
    int r = tid >> 4, cb = (tid & 15) * 8;
    const float* src = emb + (size_t)z[conf * 64 + r] * H + cb;
    float4 v0 = *(const float4*)src, v1 = *(const float4*)(src + 4);
    float vv[8] = {v0.x, v0.y, v0.z, v0.w, v1.x, v1.y, v1.z, v1.w};
    short hv[8], lv[8];
    #pragma unroll
    for (int u = 0; u < 8; u++) {
      unsigned short hb = bf16_rne(vv[u]);
      hv[u] = (short)hb;
      lv[u] = (short)bf16_rne(vv[u] - bf16_to_f(hb));
    }
    *(short8_t*)&hH[r][cb] = *(short8_t*)hv;
    *(short8_t*)&hL[r][cb] = *(short8_t*)lv;
  }
  __syncthreads();

  // xs0 = h @ cf_w1[0]
  {
    f32x4 acc[2] = {{0.f, 0.f, 0.f, 0.f}, {0.f, 0.f, 0.f, 0.f}};
    gemm_rt2(hH, hL, PW + (size_t)12 * 32768, rt2, nt, lane, quad, ln, acc);
    int col = nt * 16 + ln;
    #pragma unroll
    for (int rtt = 0; rtt < 2; rtt++)
      #pragma unroll
      for (int reg = 0; reg < 4; reg++)
        xs[rt2 * 32 + rtt * 16 + quad * 4 + reg][col] = acc[rtt][reg];
  }
  __syncthreads();

  for (int l = 0; l < NL; l++) {
    const char* Tlb = (const char*)(Tb + (size_t)l * TPB * H) + ch0 * 2;
    // ---- aggregation with ping-pong prefetch ----
    int msA[8];
    uint4 tvA[8];
    #pragma unroll
    for (int it = 0; it < 8; it++) msA[it] = pks[(w * 4) * DEG + it * 4 + eg];
    #pragma unroll
    for (int it = 0; it < 8; it++)
      tvA[it] = *(const uint4*)(Tlb + (msA[it] & 0xFFFFF));
    #pragma unroll
    for (int aa = 0; aa < 4; aa++) {
      int msB[8];
      uint4 tvB[8];
      if (aa < 3) {
        #pragma unroll
        for (int it = 0; it < 8; it++)
          msB[it] = pks[(w * 4 + aa + 1) * DEG + it * 4 + eg];
        #pragma unroll
        for (int it = 0; it < 8; it++)
          tvB[it] = *(const uint4*)(Tlb + (msB[it] & 0xFFFFF));
      }
      int a2 = w * 4 + aa;
      f32x2 ac0 = {0.f, 0.f}, ac1 = {0.f, 0.f}, ac2 = {0.f, 0.f}, ac3 = {0.f, 0.f};
      #pragma unroll
      for (int it = 0; it < 8; it++) {
        int sl = msA[it] >> 20;
        const float* xr = &xs[sl][ch0];
        float4 x0 = *(const float4*)xr;
        float4 x1 = *(const float4*)(xr + 4);
        uint4 tv = tvA[it];
        ac0 = __builtin_elementwise_fma((f32x2){bflo(tv.x), bfhi(tv.x)},
                                        (f32x2){x0.x, x0.y}, ac0);
        ac1 = __builtin_elementwise_fma((f32x2){bflo(tv.y), bfhi(tv.y)},
                                        (f32x2){x0.z, x0.w}, ac1);
        ac2 = __builtin_elementwise_fma((f32x2){bflo(tv.z), bfhi(tv.z)},
                                        (f32x2){x1.x, x1.y}, ac2);
        ac3 = __builtin_elementwise_fma((f32x2){bflo(tv.w), bfhi(tv.w)},
                                        (f32x2){x1.z, x1.w}, ac3);
      }
      float accs[8] = {ac0.x, ac0.y, ac1.x, ac1.y, ac2.x, ac2.y, ac3.x, ac3.y};
      #pragma unroll
      for (int j = 0; j < 8; j++) {
        accs[j] += __shfl_xor(accs[j], 16);
        accs[j] += __shfl_xor(accs[j], 32);
      }
      float va = eg == 0 ? accs[0] : eg == 1 ? accs[2] : eg == 2 ? accs[4] : accs[6];
      float vb = eg == 0 ? accs[1] : eg == 1 ? accs[3] : eg == 2 ? accs[5] : accs[7];
      unsigned short ha = bf16_rne(va), hb = bf16_rne(vb);
      unsigned short la = bf16_rne(va - bf16_to_f(ha));
      unsigned short lb = bf16_rne(vb - bf16_to_f(hb));
      int cw = ch0 + eg * 2;
      *(short2*)&S1H[a2][cw] = make_short2((short)ha, (short)hb);
      *(short2*)&S1L[a2][cw] = make_short2((short)la, (short)lb);
      #pragma unroll
      for (int it = 0; it < 8; it++) {
        msA[it] = msB[it];
        tvA[it] = tvB[it];
      }
    }
    __syncthreads();
    // ---- GEMM1: t = ssp(S1 @ cf_w2[l] + cf_b2[l]) ----
    {
      f32x4 acc[2] = {{0.f, 0.f, 0.f, 0.f}, {0.f, 0.f, 0.f, 0.f}};
      gemm_rt2(S1H, S1L, PW + (size_t)(2 * l) * 32768, rt2, nt, lane, quad, ln, acc);
      int col = nt * 16 + ln;
      float bb = cf_b2[l * H + col];
      #pragma unroll
      for (int rtt = 0; rtt < 2; rtt++)
        #pragma unroll
        for (int reg = 0; reg < 4; reg++) {
          int row = rt2 * 32 + rtt * 16 + quad * 4 + reg;
          float v = ssp_f(acc[rtt][reg] + bb);
          unsigned short hb = bf16_rne(v);
          tH[row][col] = (short)hb;
          tL[row][col] = (short)bf16_rne(v - bf16_to_f(hb));
        }
    }
    __syncthreads();
    // ---- GEMM2: h += t @ int_w[l] + int_b[l] ----
    {
      f32x4 acc[2] = {{0.f, 0.f, 0.f, 0.f}, {0.f, 0.f, 0.f, 0.f}};
      gemm_rt2(tH, tL, PW + (size_t)(2 * l + 1) * 32768, rt2, nt, lane, quad, ln, acc);
      int col = nt * 16 + ln;
      float bb = int_b[l * H + col];
      #pragma unroll
      for (int rtt = 0; rtt < 2; rtt++)
        #pragma unroll
        for (int reg = 0; reg < 4; reg++) {
          int row = rt2 * 32 + rtt * 16 + quad * 4 + reg;
          float hv = bf16_to_f((unsigned short)hH[row][col]) +
                     bf16_to_f((unsigned short)hL[row][col]);
          float v = acc[rtt][reg] + bb + hv;
          unsigned short hb = bf16_rne(v);
          hH[row][col] = (short)hb;
          hL[row][col] = (short)bf16_rne(v - bf16_to_f(hb));
        }
    }
    __syncthreads();
    // ---- GEMM3: xs = h @ cf_w1[l+1] ----
    if (l < NL - 1) {
      f32x4 acc[2] = {{0.f, 0.f, 0.f, 0.f}, {0.f, 0.f, 0.f, 0.f}};
      gemm_rt2(hH, hL, PW + (size_t)(13 + l) * 32768, rt2, nt, lane, quad, ln, acc);
      int col = nt * 16 + ln;
      #pragma unroll
      for (int rtt = 0; rtt < 2; rtt++)
        #pragma unroll
        for (int reg = 0; reg < 4; reg++)
          xs[rt2 * 32 + rtt * 16 + quad * 4 + reg][col] = acc[rtt][reg];
      __syncthreads();
    }
  }

  // ---- readout GEMM1: t = ssp(h @ out_w1 + out_b1) ----
  {
    f32x4 acc[2] = {{0.f, 0.f, 0.f, 0.f}, {0.f, 0.f, 0.f, 0.f}};
    gemm_rt2(hH, hL, PW + (size_t)18 * 32768, rt2, nt, lane, quad, ln, acc);
    int col = nt * 16 + ln;
    float bb = out_b1[col];
    #pragma unroll
    for (int rtt = 0; rtt < 2; rtt++)
      #pragma unroll
      for (int reg = 0; reg < 4; reg++) {
        int row = rt2 * 32 + rtt * 16 + quad * 4 + reg;
        float v = ssp_f(acc[rtt][reg] + bb);
        unsigned short hb = bf16_rne(v);
        tH[row][col] = (short)hb;
        tL[row][col] = (short)bf16_rne(v - bf16_to_f(hb));
      }
  }
  __syncthreads();
  // ---- readout GEMM2 + row-sum pool ----
  {
    f32x4 acc[2] = {{0.f, 0.f, 0.f, 0.f}, {0.f, 0.f, 0.f, 0.f}};
    gemm_rt2(tH, tL, PW + (size_t)19 * 32768, rt2, nt, lane, quad, ln, acc);
    int col = nt * 16 + ln;
    float s = acc[0][0] + acc[0][1] + acc[0][2] + acc[0][3] +
              acc[1][0] + acc[1][1] + acc[1][2] + acc[1][3];
    s += __shfl_xor(s, 16);
    s += __shfl_xor(s, 32);
    if (quad == 0) ps[rt2][col] = s;
  }
  __syncthreads();
  if (tid < 128) {
    float v = ps[0][tid] + ps[1][tid] + 64.f * out_b2[tid];
    __hip_atomic_store(&ce[conf * 128 + tid], v, __ATOMIC_RELAXED,
                       __HIP_MEMORY_SCOPE_AGENT);
  }
  __syncthreads();
  if (tid == 0) {
    __threadfence();
    int old = __hip_atomic_fetch_add(&cnt[2], 1, __ATOMIC_ACQ_REL,
                                     __HIP_MEMORY_SCOPE_AGENT);
    *is_last = (old == N_CONF - 1) ? 1 : 0;
  }
  __syncthreads();
  if (*is_last) {
    __threadfence();
    float* mol = &xs[0][0];         // 64*128 floats
    for (int t = tid; t < N_MOL * 128; t += 1024) {
      int m = t >> 7, c = t & 127;
      const float* bb = ce + (size_t)(m * 4) * 128;
      float s = __hip_atomic_load(&bb[c], __ATOMIC_RELAXED, __HIP_MEMORY_SCOPE_AGENT) +
                __hip_atomic_load(&bb[128 + c], __ATOMIC_RELAXED, __HIP_MEMORY_SCOPE_AGENT) +
                __hip_atomic_load(&bb[256 + c], __ATOMIC_RELAXED, __HIP_MEMORY_SCOPE_AGENT) +
                __hip_atomic_load(&bb[384 + c], __ATOMIC_RELAXED, __HIP_MEMORY_SCOPE_AGENT);
      mol[t] = s;
    }
    __syncthreads();
    float* q = (float*)&S1H[0][0];  // 64*64 floats
    for (int t = tid; t < N_MOL * 64; t += 1024) {
      int m = t >> 6, j = t & 63;
      float qq = hb1[j];
      #pragma unroll 8
      for (int c = 0; c < H; c++) qq += mol[m * 128 + c] * hw1[c * 64 + j];
      q[t] = ssp_f(qq);
    }
    __syncthreads();
    if (tid < N_MOL) {
      float o = hb2[0];
      #pragma unroll 8
      for (int j = 0; j < 64; j++) o += q[tid * 64 + j] * hw2[j];
      outp[tid] = o;
    }
  }
}

extern "C" void kernel_launch(void* const* d_in, const int* in_sizes, int n_in,
                              void* d_out, int out_size, void* d_ws, size_t ws_size,
                              hipStream_t stream) {
  const int*   z       = (const int*)d_in[0];
  const float* pos     = (const float*)d_in[1];
  const int*   eidx    = (const int*)d_in[2];
  const float* emb     = (const float*)d_in[5];
  const float* mlp_w1  = (const float*)d_in[6];
  const float* mlp_b1  = (const float*)d_in[7];
  const float* mlp_w2  = (const float*)d_in[8];
  const float* mlp_b2  = (const float*)d_in[9];
  const float* cf_w1   = (const float*)d_in[10];
  const float* cf_w2   = (const float*)d_in[11];
  const float* cf_b2   = (const float*)d_in[12];
  const float* int_w   = (const float*)d_in[13];
  const float* int_b   = (const float*)d_in[14];
  const float* out_w1  = (const float*)d_in[15];
  const float* out_b1  = (const float*)d_in[16];
  const float* out_w2  = (const float*)d_in[17];
  const float* out_b2  = (const float*)d_in[18];
  const float* head_w1 = (const float*)d_in[19];
  const float* head_b1 = (const float*)d_in[20];
  const float* head_w2 = (const float*)d_in[21];
  const float* head_b2 = (const float*)d_in[22];

  char* ws = (char*)d_ws;
  float*          T   = (float*)ws;                             // 1,572,864 B
  unsigned short* Tb  = (unsigned short*)(ws + 1572864);        // 6,291,456 B
  short*          PW  = (short*)(ws + 1572864 + 6291456);       // 1,310,720 B
  float*          ce  = (float*)(ws + 9175040);                 //   131,072 B
  int*            cnt = (int*)(ws + 9306112);                   //        12 B

  hipMemsetAsync(cnt, 0, 12, stream);
  k_all<<<N_CONF, 1024, 0, stream>>>(
      z, pos, eidx, emb, mlp_w1, mlp_b1, mlp_w2, mlp_b2,
      cf_w1, cf_w2, cf_b2, int_w, int_b, out_w1, out_b1, out_w2, out_b2,
      head_w1, head_b1, head_w2, head_b2,
      T, Tb, PW, ce, cnt, (float*)d_out);
}

// Round 10
// 271.806 us; speedup vs baseline: 1.9726x; 1.9726x over previous
//
#include <hip/hip_runtime.h>
#include <math.h>

#define N_ATOMS 16384
#define APC 64
#define N_CONF 256
#define N_MOL 64
#define DEG 32
#define NEDGE (N_ATOMS * DEG)
#define H 128
#define G 50
#define NL 6
#define TP0 512          // fp32 source table points
#define TPB 4096         // bf16 nearest table points
#define CUTOFF 10.0f

typedef __attribute__((ext_vector_type(8))) short short8_t;
typedef __attribute__((ext_vector_type(4))) float f32x4;

__device__ __forceinline__ float ssp_f(float x) {
  float e = __expf(-fabsf(x));
  return fmaxf(x, 0.f) + __logf(1.f + e) - 0.69314718055994531f;
}
__device__ __forceinline__ unsigned short bf16_rne(float x) {
  unsigned u = __float_as_uint(x);
  unsigned r = u + 0x7FFF + ((u >> 16) & 1);
  return (unsigned short)(r >> 16);
}
__device__ __forceinline__ float bf16_to_f(unsigned short s) {
  return __uint_as_float(((unsigned)s) << 16);
}
__device__ __forceinline__ float bflo(unsigned u) { return __uint_as_float(u << 16); }
__device__ __forceinline__ float bfhi(unsigned u) { return __uint_as_float(u & 0xFFFF0000u); }

// Fused setup: [0,160) weight swizzle | [160,1696) fp32 table
__global__ __launch_bounds__(256) void k_setup(
    const float* __restrict__ cf_w1, const float* __restrict__ cf_w2,
    const float* __restrict__ int_w, const float* __restrict__ out_w1,
    const float* __restrict__ out_w2, short* __restrict__ PW,
    const float* __restrict__ w1, const float* __restrict__ b1,
    const float* __restrict__ w2, const float* __restrict__ b2,
    float* __restrict__ T) {
  __shared__ float g2[2][64];
  __shared__ float S2[2][128];
  const int b = blockIdx.x;
  const int tid = threadIdx.x;
  if (b < 160) {
    // weight pre-swizzle into MFMA B-fragment order (bf16 hi/lo)
    int e = b * 256 + tid;   // < 20*2048
    int g = e >> 11, t = e & 2047;
    int kb = t >> 9, rem = t & 511, nt = rem >> 6, lane = rem & 63;
    int quad = lane >> 4, ln = lane & 15;
    int kbase = kb * 32 + quad * 8;
    int n = nt * 16 + ln;
    const float* src;
    if (g < 12) {
      int l = g >> 1;
      src = (g & 1) ? (int_w + l * 16384) : (cf_w2 + l * 16384);
    } else if (g < 18) {
      src = cf_w1 + (g - 12) * 16384;
    } else {
      src = (g == 18) ? out_w1 : out_w2;
    }
    short hv[8], lv[8];
    #pragma unroll
    for (int j = 0; j < 8; j++) {
      float x = src[(kbase + j) * H + n];
      unsigned short hb = bf16_rne(x);
      hv[j] = (short)hb;
      lv[j] = (short)bf16_rne(x - bf16_to_f(hb));
    }
    size_t base = (size_t)g * 32768 + (size_t)t * 8;
    *(short8_t*)&PW[base] = *(short8_t*)hv;
    *(short8_t*)&PW[base + 16384] = *(short8_t*)lv;
  } else {
    int bb = b - 160;
    const int l = bb >> 8;               // TP0/2 = 256 blocks/layer
    const int grp = tid >> 7;
    const int c = tid & 127;
    const int p = (bb & 255) * 2 + grp;
    const float d = (float)p * (CUTOFF / (float)(TP0 - 1));
    const float gspace = CUTOFF / (float)(G - 1);
    const float coeff = -0.5f / (gspace * gspace);
    if (c < G) {
      float x = d - (float)c * gspace;
      g2[grp][c] = __expf(coeff * x * x);
    }
    __syncthreads();
    const float* W1 = w1 + l * G * H;
    float s = b1[l * H + c];
    #pragma unroll 5
    for (int i = 0; i < G; i++) s += g2[grp][i] * W1[i * H + c];
    S2[grp][c] = ssp_f(s);
    __syncthreads();
    const float* W2 = w2 + l * H * H;
    float o = b2[l * H + c];
    #pragma unroll 8
    for (int j = 0; j < H; j++) o += S2[grp][j] * W2[j * H + c];
    float Cc = 0.5f * (__cosf(d * (3.14159265358979f / CUTOFF)) + 1.f);
    T[((size_t)l * TP0 + p) * H + c] = o * Cc;
  }
}

// upsample fp32 TP0 table -> bf16 TPB nearest table via lerp; 4 ch per thread
__global__ __launch_bounds__(256) void k_up(const float* __restrict__ T,
                                            unsigned short* __restrict__ Tb) {
  int t = blockIdx.x * 256 + threadIdx.x;   // < NL*TPB*H/4
  int l = t >> 17;                          // TPB*H/4 = 131072
  int rem = t & 131071;
  int p4 = rem >> 5, cg = rem & 31;
  int c = cg * 4;
  float u = (float)p4 * ((float)(TP0 - 1) / (float)(TPB - 1));
  int i = (int)u;
  if (i > TP0 - 2) i = TP0 - 2;
  float f = u - (float)i;
  const float* a = T + ((size_t)l * TP0 + i) * H + c;
  float4 v0 = *(const float4*)a;
  float4 v1 = *(const float4*)(a + H);
  ushort4 o;
  o.x = bf16_rne(v0.x + f * (v1.x - v0.x));
  o.y = bf16_rne(v0.y + f * (v1.y - v0.y));
  o.z = bf16_rne(v0.z + f * (v1.z - v0.z));
  o.w = bf16_rne(v0.w + f * (v1.w - v0.w));
  *(ushort4*)&Tb[((size_t)l * TPB + p4) * H + c] = o;
}

#define MFMA(a, b, c) __builtin_amdgcn_mfma_f32_16x16x32_bf16((a), (b), (c), 0, 0, 0)

__device__ __forceinline__ void load_afrags(const short (*AH)[136], const short (*AL)[136],
                                            int rt, int ln, int quad,
                                            short8_t ah[4], short8_t al[4]) {
  #pragma unroll
  for (int kb = 0; kb < 4; kb++) {
    int ko = kb * 32 + quad * 8;
    ah[kb] = *(const short8_t*)&AH[rt * 16 + ln][ko];
    al[kb] = *(const short8_t*)&AL[rt * 16 + ln][ko];
  }
}

// 2 col-tiles per wave
__device__ __forceinline__ void gemm2w(const short8_t ah[4], const short8_t al[4],
                                       const short* __restrict__ pw, int nt0, int lane,
                                       f32x4 acc[2]) {
  #pragma unroll
  for (int ct = 0; ct < 2; ct++) {
    int nt = nt0 + ct;
    f32x4 a = {0.f, 0.f, 0.f, 0.f};
    #pragma unroll
    for (int kb = 0; kb < 4; kb++) {
      const short* pb = pw + ((size_t)(kb * 8 + nt) * 64 + lane) * 8;
      short8_t bh = *(const short8_t*)pb;
      short8_t bl = *(const short8_t*)(pb + 16384);
      a = MFMA(ah[kb], bh, a);
      a = MFMA(ah[kb], bl, a);
      a = MFMA(al[kb], bh, a);
    }
    acc[ct] = a;
  }
}

// Persistent per-conformer kernel + fused mol pool/head in last block.
__global__ __launch_bounds__(1024, 1) void k_mega(
    const int* __restrict__ z, const float* __restrict__ pos,
    const int* __restrict__ esrc, const float* __restrict__ emb,
    const unsigned short* __restrict__ Tb, const short* __restrict__ PW,
    const float* __restrict__ cf_b2, const float* __restrict__ int_b,
    const float* __restrict__ out_b1, const float* __restrict__ out_b2,
    float* __restrict__ ce, const float* __restrict__ hw1,
    const float* __restrict__ hb1, const float* __restrict__ hw2,
    const float* __restrict__ hb2, int* __restrict__ cnt,
    float* __restrict__ outp) {
  __shared__ float xs[64][132];                               // xf, fp32
  __shared__ __align__(16) short hH[64][136], hL[64][136];    // h
  __shared__ __align__(16) short S1H[64][136], S1L[64][136];  // agg / t
  __shared__ int pks[2048];
  __shared__ float ps[4][128];
  __shared__ float posL[192];
  __shared__ int is_last;
  const int conf = blockIdx.x;
  const int tid = threadIdx.x;
  const int lane = tid & 63, w = tid >> 6;       // 16 waves
  const int quad = lane >> 4, ln = lane & 15;
  const int rt = w & 3, nt0 = (w >> 2) * 2;      // 4 row-tiles x 4 col-groups(2 tiles)
  const int eg = lane >> 4, ch0 = (lane & 15) * 8;

  // stage conformer positions, then local edge records
  if (tid < 192) posL[tid] = pos[conf * 192 + tid];
  __syncthreads();
  #pragma unroll
  for (int k = 0; k < 2; k++) {
    int e2 = k * 1024 + tid;
    int r = esrc[conf * 2048 + e2];
    int rl = r & (APC - 1);
    int ca = e2 >> 5;
    float dx = posL[rl * 3 + 0] - posL[ca * 3 + 0];
    float dy = posL[rl * 3 + 1] - posL[ca * 3 + 1];
    float dz = posL[rl * 3 + 2] - posL[ca * 3 + 2];
    float d = sqrtf(dx * dx + dy * dy + dz * dz);
    int i = (int)(d * ((float)(TPB - 1) / CUTOFF) + 0.5f);
    if (i > TPB - 1) i = TPB - 1;
    if (i < 0) i = 0;
    pks[e2] = i | (rl << 16);
  }
  // init h from emb
  {
    int r = tid >> 4, cb = (tid & 15) * 8;
    const float* src = emb + (size_t)z[conf * 64 + r] * H + cb;
    float4 v0 = *(const float4*)src, v1 = *(const float4*)(src + 4);
    float vv[8] = {v0.x, v0.y, v0.z, v0.w, v1.x, v1.y, v1.z, v1.w};
    short hv[8], lv[8];
    #pragma unroll
    for (int u = 0; u < 8; u++) {
      unsigned short hb = bf16_rne(vv[u]);
      hv[u] = (short)hb;
      lv[u] = (short)bf16_rne(vv[u] - bf16_to_f(hb));
    }
    *(short8_t*)&hH[r][cb] = *(short8_t*)hv;
    *(short8_t*)&hL[r][cb] = *(short8_t*)lv;
  }
  __syncthreads();

  // xs0 = h @ cf_w1[0]
  {
    short8_t ah[4], al_[4];
    load_afrags(hH, hL, rt, ln, quad, ah, al_);
    f32x4 acc[2];
    gemm2w(ah, al_, PW + (size_t)12 * 32768, nt0, lane, acc);
    #pragma unroll
    for (int ct = 0; ct < 2; ct++)
      #pragma unroll
      for (int reg = 0; reg < 4; reg++)
        xs[rt * 16 + quad * 4 + reg][(nt0 + ct) * 16 + ln] = acc[ct][reg];
  }
  __syncthreads();

  for (int l = 0; l < NL; l++) {
    const unsigned short* Tl = Tb + (size_t)l * TPB * H;
    // ---- aggregation: S1 = split( sum_e T[idx_e] * xs[src_e] ) ----
    #pragma unroll
    for (int aa = 0; aa < 4; aa++) {
      int a2 = w * 4 + aa;
      float acc[8] = {};
      #pragma unroll
      for (int it = 0; it < 8; it++) {
        int m = pks[a2 * DEG + it * 4 + eg];
        int idx = m & 0xFFFF, sl = m >> 16;
        uint4 tv = *(const uint4*)&Tl[(size_t)idx * H + ch0];
        float4 x0 = *(const float4*)&xs[sl][ch0];
        float4 x1 = *(const float4*)&xs[sl][ch0 + 4];
        acc[0] += bflo(tv.x) * x0.x; acc[1] += bfhi(tv.x) * x0.y;
        acc[2] += bflo(tv.y) * x0.z; acc[3] += bfhi(tv.y) * x0.w;
        acc[4] += bflo(tv.z) * x1.x; acc[5] += bfhi(tv.z) * x1.y;
        acc[6] += bflo(tv.w) * x1.z; acc[7] += bfhi(tv.w) * x1.w;
      }
      #pragma unroll
      for (int j = 0; j < 8; j++) {
        acc[j] += __shfl_xor(acc[j], 16);
        acc[j] += __shfl_xor(acc[j], 32);
      }
      if (eg == 0) {
        short hv[8], lv[8];
        #pragma unroll
        for (int j = 0; j < 8; j++) {
          unsigned short hb = bf16_rne(acc[j]);
          hv[j] = (short)hb;
          lv[j] = (short)bf16_rne(acc[j] - bf16_to_f(hb));
        }
        *(short8_t*)&S1H[a2][ch0] = *(short8_t*)hv;
        *(short8_t*)&S1L[a2][ch0] = *(short8_t*)lv;
      }
    }
    __syncthreads();
    // ---- GEMM1: t = ssp(S1 @ cf_w2[l] + cf_b2[l]) -> S1 ----
    {
      short8_t ah[4], al_[4];
      load_afrags(S1H, S1L, rt, ln, quad, ah, al_);
      f32x4 acc[2];
      gemm2w(ah, al_, PW + (size_t)(2 * l) * 32768, nt0, lane, acc);
      __syncthreads();
      #pragma unroll
      for (int ct = 0; ct < 2; ct++) {
        int col = (nt0 + ct) * 16 + ln;
        float bb = cf_b2[l * H + col];
        #pragma unroll
        for (int reg = 0; reg < 4; reg++) {
          int row = rt * 16 + quad * 4 + reg;
          float v = ssp_f(acc[ct][reg] + bb);
          unsigned short hb = bf16_rne(v);
          S1H[row][col] = (short)hb;
          S1L[row][col] = (short)bf16_rne(v - bf16_to_f(hb));
        }
      }
    }
    __syncthreads();
    // ---- GEMM2: h += t @ int_w[l] + int_b[l] ----
    {
      short8_t ah[4], al_[4];
      load_afrags(S1H, S1L, rt, ln, quad, ah, al_);
      f32x4 acc[2];
      gemm2w(ah, al_, PW + (size_t)(2 * l + 1) * 32768, nt0, lane, acc);
      #pragma unroll
      for (int ct = 0; ct < 2; ct++) {
        int col = (nt0 + ct) * 16 + ln;
        float bb = int_b[l * H + col];
        #pragma unroll
        for (int reg = 0; reg < 4; reg++) {
          int row = rt * 16 + quad * 4 + reg;
          float hv = bf16_to_f((unsigned short)hH[row][col]) +
                     bf16_to_f((unsigned short)hL[row][col]);
          float v = acc[ct][reg] + bb + hv;
          unsigned short hb = bf16_rne(v);
          hH[row][col] = (short)hb;
          hL[row][col] = (short)bf16_rne(v - bf16_to_f(hb));
        }
      }
    }
    __syncthreads();
    // ---- GEMM3: xs = h @ cf_w1[l+1] ----
    if (l < NL - 1) {
      short8_t ah[4], al_[4];
      load_afrags(hH, hL, rt, ln, quad, ah, al_);
      f32x4 acc[2];
      gemm2w(ah, al_, PW + (size_t)(13 + l) * 32768, nt0, lane, acc);
      #pragma unroll
      for (int ct = 0; ct < 2; ct++)
        #pragma unroll
        for (int reg = 0; reg < 4; reg++)
          xs[rt * 16 + quad * 4 + reg][(nt0 + ct) * 16 + ln] = acc[ct][reg];
      __syncthreads();
    }
  }

  // ---- readout GEMM1: S1 = ssp(h @ out_w1 + out_b1) ----
  {
    short8_t ah[4], al_[4];
    load_afrags(hH, hL, rt, ln, quad, ah, al_);
    f32x4 acc[2];
    gemm2w(ah, al_, PW + (size_t)18 * 32768, nt0, lane, acc);
    __syncthreads();
    #pragma unroll
    for (int ct = 0; ct < 2; ct++) {
      int col = (nt0 + ct) * 16 + ln;
      float bb = out_b1[col];
      #pragma unroll
      for (int reg = 0; reg < 4; reg++) {
        int row = rt * 16 + quad * 4 + reg;
        float v = ssp_f(acc[ct][reg] + bb);
        unsigned short hb = bf16_rne(v);
        S1H[row][col] = (short)hb;
        S1L[row][col] = (short)bf16_rne(v - bf16_to_f(hb));
      }
    }
  }
  __syncthreads();
  // ---- readout GEMM2 + row-sum pool ----
  {
    short8_t ah[4], al_[4];
    load_afrags(S1H, S1L, rt, ln, quad, ah, al_);
    f32x4 acc[2];
    gemm2w(ah, al_, PW + (size_t)19 * 32768, nt0, lane, acc);
    #pragma unroll
    for (int ct = 0; ct < 2; ct++) {
      int col = (nt0 + ct) * 16 + ln;
      float s = acc[ct][0] + acc[ct][1] + acc[ct][2] + acc[ct][3];
      s += __shfl_xor(s, 16);
      s += __shfl_xor(s, 32);
      if (quad == 0) ps[rt][col] = s;
    }
  }
  __syncthreads();
  if (tid < 128) {
    float v = ps[0][tid] + ps[1][tid] + ps[2][tid] + ps[3][tid] + 64.f * out_b2[tid];
    __hip_atomic_store(&ce[conf * 128 + tid], v, __ATOMIC_RELAXED,
                       __HIP_MEMORY_SCOPE_AGENT);
  }
  __syncthreads();
  if (tid == 0) {
    __threadfence();
    int old = __hip_atomic_fetch_add(cnt, 1, __ATOMIC_ACQ_REL,
                                     __HIP_MEMORY_SCOPE_AGENT);
    is_last = (old == N_CONF - 1) ? 1 : 0;
  }
  __syncthreads();
  if (is_last) {
    __threadfence();
    float* mol = &xs[0][0];         // 64*128 floats (flat scratch)
    for (int t = tid; t < N_MOL * 128; t += 1024) {
      int m = t >> 7, c = t & 127;
      const float* bb = ce + (size_t)(m * 4) * 128;
      float s = __hip_atomic_load(&bb[c], __ATOMIC_RELAXED, __HIP_MEMORY_SCOPE_AGENT) +
                __hip_atomic_load(&bb[128 + c], __ATOMIC_RELAXED, __HIP_MEMORY_SCOPE_AGENT) +
                __hip_atomic_load(&bb[256 + c], __ATOMIC_RELAXED, __HIP_MEMORY_SCOPE_AGENT) +
                __hip_atomic_load(&bb[384 + c], __ATOMIC_RELAXED, __HIP_MEMORY_SCOPE_AGENT);
      mol[t] = s;
    }
    __syncthreads();
    float* q = (float*)&S1H[0][0];  // 64*64 floats (flat scratch)
    for (int t = tid; t < N_MOL * 64; t += 1024) {
      int m = t >> 6, j = t & 63;
      float qq = hb1[j];
      #pragma unroll 8
      for (int c = 0; c < H; c++) qq += mol[m * 128 + c] * hw1[c * 64 + j];
      q[t] = ssp_f(qq);
    }
    __syncthreads();
    if (tid < N_MOL) {
      float o = hb2[0];
      #pragma unroll 8
      for (int j = 0; j < 64; j++) o += q[tid * 64 + j] * hw2[j];
      outp[tid] = o;
    }
  }
}

extern "C" void kernel_launch(void* const* d_in, const int* in_sizes, int n_in,
                              void* d_out, int out_size, void* d_ws, size_t ws_size,
                              hipStream_t stream) {
  const int*   z       = (const int*)d_in[0];
  const float* pos     = (const float*)d_in[1];
  const int*   eidx    = (const int*)d_in[2];
  const float* emb     = (const float*)d_in[5];
  const float* mlp_w1  = (const float*)d_in[6];
  const float* mlp_b1  = (const float*)d_in[7];
  const float* mlp_w2  = (const float*)d_in[8];
  const float* mlp_b2  = (const float*)d_in[9];
  const float* cf_w1   = (const float*)d_in[10];
  const float* cf_w2   = (const float*)d_in[11];
  const float* cf_b2   = (const float*)d_in[12];
  const float* int_w   = (const float*)d_in[13];
  const float* int_b   = (const float*)d_in[14];
  const float* out_w1  = (const float*)d_in[15];
  const float* out_b1  = (const float*)d_in[16];
  const float* out_w2  = (const float*)d_in[17];
  const float* out_b2  = (const float*)d_in[18];
  const float* head_w1 = (const float*)d_in[19];
  const float* head_b1 = (const float*)d_in[20];
  const float* head_w2 = (const float*)d_in[21];
  const float* head_b2 = (const float*)d_in[22];

  char* ws = (char*)d_ws;
  float*          T   = (float*)ws;                             // 1,572,864 B
  unsigned short* Tb  = (unsigned short*)(ws + 1572864);        // 6,291,456 B
  short*          PW  = (short*)(ws + 1572864 + 6291456);       // 1,310,720 B
  float*          ce  = (float*)(ws + 9175040);                 //   131,072 B
  int*            cnt = (int*)(ws + 9306112);                   //         4 B

  hipMemsetAsync(cnt, 0, 4, stream);
  k_setup<<<1696, 256, 0, stream>>>(cf_w1, cf_w2, int_w, out_w1, out_w2, PW,
                                    mlp_w1, mlp_b1, mlp_w2, mlp_b2, T);
  k_up<<<(NL * TPB * H / 4) / 256, 256, 0, stream>>>(T, Tb);
  k_mega<<<N_CONF, 1024, 0, stream>>>(z, pos, eidx, emb, Tb, PW, cf_b2, int_b,
                                      out_b1, out_b2, ce,
                                      head_w1, head_b1, head_w2, head_b2,
                                      cnt, (float*)d_out);
}

// Round 11
// 260.218 us; speedup vs baseline: 2.0604x; 1.0445x over previous
//
#include <hip/hip_runtime.h>
#include <math.h>

#define N_ATOMS 16384
#define APC 64
#define N_CONF 256
#define N_MOL 64
#define DEG 32
#define NEDGE (N_ATOMS * DEG)
#define H 128
#define G 50
#define NL 6
#define TP0 512          // fp32 source table points
#define TPB 4096         // bf16 nearest table points
#define CUTOFF 10.0f

typedef __attribute__((ext_vector_type(8))) short short8_t;
typedef __attribute__((ext_vector_type(4))) float f32x4;

__device__ __forceinline__ float ssp_f(float x) {
  float e = __expf(-fabsf(x));
  return fmaxf(x, 0.f) + __logf(1.f + e) - 0.69314718055994531f;
}
__device__ __forceinline__ unsigned short bf16_rne(float x) {
  unsigned u = __float_as_uint(x);
  unsigned r = u + 0x7FFF + ((u >> 16) & 1);
  return (unsigned short)(r >> 16);
}
__device__ __forceinline__ float bf16_to_f(unsigned short s) {
  return __uint_as_float(((unsigned)s) << 16);
}
__device__ __forceinline__ float bflo(unsigned u) { return __uint_as_float(u << 16); }
__device__ __forceinline__ float bfhi(unsigned u) { return __uint_as_float(u & 0xFFFF0000u); }

// Fused setup: [0,160) weight swizzle | [160,1696) fp32 table
__global__ __launch_bounds__(256) void k_setup(
    const float* __restrict__ cf_w1, const float* __restrict__ cf_w2,
    const float* __restrict__ int_w, const float* __restrict__ out_w1,
    const float* __restrict__ out_w2, short* __restrict__ PW,
    const float* __restrict__ w1, const float* __restrict__ b1,
    const float* __restrict__ w2, const float* __restrict__ b2,
    float* __restrict__ T) {
  __shared__ float g2[2][64];
  __shared__ float S2[2][128];
  const int b = blockIdx.x;
  const int tid = threadIdx.x;
  if (b < 160) {
    // weight pre-swizzle into MFMA B-fragment order (bf16 hi/lo)
    int e = b * 256 + tid;   // < 20*2048
    int g = e >> 11, t = e & 2047;
    int kb = t >> 9, rem = t & 511, nt = rem >> 6, lane = rem & 63;
    int quad = lane >> 4, ln = lane & 15;
    int kbase = kb * 32 + quad * 8;
    int n = nt * 16 + ln;
    const float* src;
    if (g < 12) {
      int l = g >> 1;
      src = (g & 1) ? (int_w + l * 16384) : (cf_w2 + l * 16384);
    } else if (g < 18) {
      src = cf_w1 + (g - 12) * 16384;
    } else {
      src = (g == 18) ? out_w1 : out_w2;
    }
    short hv[8], lv[8];
    #pragma unroll
    for (int j = 0; j < 8; j++) {
      float x = src[(kbase + j) * H + n];
      unsigned short hb = bf16_rne(x);
      hv[j] = (short)hb;
      lv[j] = (short)bf16_rne(x - bf16_to_f(hb));
    }
    size_t base = (size_t)g * 32768 + (size_t)t * 8;
    *(short8_t*)&PW[base] = *(short8_t*)hv;
    *(short8_t*)&PW[base + 16384] = *(short8_t*)lv;
  } else {
    int bb = b - 160;
    const int l = bb >> 8;               // TP0/2 = 256 blocks/layer
    const int grp = tid >> 7;
    const int c = tid & 127;
    const int p = (bb & 255) * 2 + grp;
    const float d = (float)p * (CUTOFF / (float)(TP0 - 1));
    const float gspace = CUTOFF / (float)(G - 1);
    const float coeff = -0.5f / (gspace * gspace);
    if (c < G) {
      float x = d - (float)c * gspace;
      g2[grp][c] = __expf(coeff * x * x);
    }
    __syncthreads();
    const float* W1 = w1 + l * G * H;
    float s = b1[l * H + c];
    #pragma unroll 5
    for (int i = 0; i < G; i++) s += g2[grp][i] * W1[i * H + c];
    S2[grp][c] = ssp_f(s);
    __syncthreads();
    const float* W2 = w2 + l * H * H;
    float o = b2[l * H + c];
    #pragma unroll 8
    for (int j = 0; j < H; j++) o += S2[grp][j] * W2[j * H + c];
    float Cc = 0.5f * (__cosf(d * (3.14159265358979f / CUTOFF)) + 1.f);
    T[((size_t)l * TP0 + p) * H + c] = o * Cc;
  }
}

// upsample fp32 TP0 table -> bf16 TPB nearest table via lerp; 4 ch per thread
__global__ __launch_bounds__(256) void k_up(const float* __restrict__ T,
                                            unsigned short* __restrict__ Tb) {
  int t = blockIdx.x * 256 + threadIdx.x;   // < NL*TPB*H/4
  int l = t >> 17;                          // TPB*H/4 = 131072
  int rem = t & 131071;
  int p4 = rem >> 5, cg = rem & 31;
  int c = cg * 4;
  float u = (float)p4 * ((float)(TP0 - 1) / (float)(TPB - 1));
  int i = (int)u;
  if (i > TP0 - 2) i = TP0 - 2;
  float f = u - (float)i;
  const float* a = T + ((size_t)l * TP0 + i) * H + c;
  float4 v0 = *(const float4*)a;
  float4 v1 = *(const float4*)(a + H);
  ushort4 o;
  o.x = bf16_rne(v0.x + f * (v1.x - v0.x));
  o.y = bf16_rne(v0.y + f * (v1.y - v0.y));
  o.z = bf16_rne(v0.z + f * (v1.z - v0.z));
  o.w = bf16_rne(v0.w + f * (v1.w - v0.w));
  *(ushort4*)&Tb[((size_t)l * TPB + p4) * H + c] = o;
}

#define MFMA(a, b, c) __builtin_amdgcn_mfma_f32_16x16x32_bf16((a), (b), (c), 0, 0, 0)

__device__ __forceinline__ void load_afrags(const short (*AH)[136], const short (*AL)[136],
                                            int rt, int ln, int quad,
                                            short8_t ah[4], short8_t al[4]) {
  #pragma unroll
  for (int kb = 0; kb < 4; kb++) {
    int ko = kb * 32 + quad * 8;
    ah[kb] = *(const short8_t*)&AH[rt * 16 + ln][ko];
    al[kb] = *(const short8_t*)&AL[rt * 16 + ln][ko];
  }
}

// 2 col-tiles per wave
__device__ __forceinline__ void gemm2w(const short8_t ah[4], const short8_t al[4],
                                       const short* __restrict__ pw, int nt0, int lane,
                                       f32x4 acc[2]) {
  #pragma unroll
  for (int ct = 0; ct < 2; ct++) {
    int nt = nt0 + ct;
    f32x4 a = {0.f, 0.f, 0.f, 0.f};
    #pragma unroll
    for (int kb = 0; kb < 4; kb++) {
      const short* pb = pw + ((size_t)(kb * 8 + nt) * 64 + lane) * 8;
      short8_t bh = *(const short8_t*)pb;
      short8_t bl = *(const short8_t*)(pb + 16384);
      a = MFMA(ah[kb], bh, a);
      a = MFMA(ah[kb], bl, a);
      a = MFMA(al[kb], bh, a);
    }
    acc[ct] = a;
  }
}

// Persistent per-conformer kernel + fused mol pool/head in last block.
__global__ __launch_bounds__(1024, 1) void k_mega(
    const int* __restrict__ z, const float* __restrict__ pos,
    const int* __restrict__ esrc, const float* __restrict__ emb,
    const unsigned short* __restrict__ Tb, const short* __restrict__ PW,
    const float* __restrict__ cf_b2, const float* __restrict__ int_b,
    const float* __restrict__ out_b1, const float* __restrict__ out_b2,
    float* __restrict__ ce, const float* __restrict__ hw1,
    const float* __restrict__ hb1, const float* __restrict__ hw2,
    const float* __restrict__ hb2, int* __restrict__ cnt,
    float* __restrict__ outp) {
  __shared__ float xs[64][132];                               // xf, fp32
  __shared__ __align__(16) short hH[64][136], hL[64][136];    // h
  __shared__ __align__(16) short S1H[64][136], S1L[64][136];  // agg / t
  __shared__ int pks[2048];
  __shared__ float ps[4][128];
  __shared__ float posL[192];
  __shared__ int is_last;
  const int conf = blockIdx.x;
  const int tid = threadIdx.x;
  const int lane = tid & 63, w = tid >> 6;       // 16 waves
  const int quad = lane >> 4, ln = lane & 15;
  const int rt = w & 3, nt0 = (w >> 2) * 2;      // 4 row-tiles x 4 col-groups(2 tiles)
  const int eg = lane >> 4, ch0 = (lane & 15) * 8;

  // stage conformer positions, then local edge records
  if (tid < 192) posL[tid] = pos[conf * 192 + tid];
  __syncthreads();
  #pragma unroll
  for (int k = 0; k < 2; k++) {
    int e2 = k * 1024 + tid;
    int r = esrc[conf * 2048 + e2];
    int rl = r & (APC - 1);
    int ca = e2 >> 5;
    float dx = posL[rl * 3 + 0] - posL[ca * 3 + 0];
    float dy = posL[rl * 3 + 1] - posL[ca * 3 + 1];
    float dz = posL[rl * 3 + 2] - posL[ca * 3 + 2];
    float d = sqrtf(dx * dx + dy * dy + dz * dz);
    int i = (int)(d * ((float)(TPB - 1) / CUTOFF) + 0.5f);
    if (i > TPB - 1) i = TPB - 1;
    if (i < 0) i = 0;
    pks[e2] = i | (rl << 16);
  }
  // init h from emb
  {
    int r = tid >> 4, cb = (tid & 15) * 8;
    const float* src = emb + (size_t)z[conf * 64 + r] * H + cb;
    float4 v0 = *(const float4*)src, v1 = *(const float4*)(src + 4);
    float vv[8] = {v0.x, v0.y, v0.z, v0.w, v1.x, v1.y, v1.z, v1.w};
    short hv[8], lv[8];
    #pragma unroll
    for (int u = 0; u < 8; u++) {
      unsigned short hb = bf16_rne(vv[u]);
      hv[u] = (short)hb;
      lv[u] = (short)bf16_rne(vv[u] - bf16_to_f(hb));
    }
    *(short8_t*)&hH[r][cb] = *(short8_t*)hv;
    *(short8_t*)&hL[r][cb] = *(short8_t*)lv;
  }
  __syncthreads();

  // xs0 = h @ cf_w1[0]
  {
    short8_t ah[4], al_[4];
    load_afrags(hH, hL, rt, ln, quad, ah, al_);
    f32x4 acc[2];
    gemm2w(ah, al_, PW + (size_t)12 * 32768, nt0, lane, acc);
    #pragma unroll
    for (int ct = 0; ct < 2; ct++)
      #pragma unroll
      for (int reg = 0; reg < 4; reg++)
        xs[rt * 16 + quad * 4 + reg][(nt0 + ct) * 16 + ln] = acc[ct][reg];
  }
  __syncthreads();

  for (int l = 0; l < NL; l++) {
    const unsigned short* Tl = Tb + (size_t)l * TPB * H;
    // ---- aggregation: batched 8-load prefetch per atom (R7 structure) ----
    #pragma unroll 1
    for (int aa = 0; aa < 4; aa++) {
      int a2 = w * 4 + aa;
      int ms[8];
      uint4 tvv[8];
      #pragma unroll
      for (int it = 0; it < 8; it++) ms[it] = pks[a2 * DEG + it * 4 + eg];
      #pragma unroll
      for (int it = 0; it < 8; it++)
        tvv[it] = *(const uint4*)&Tl[(size_t)(ms[it] & 0xFFFF) * H + ch0];
      float acc[8] = {};
      #pragma unroll
      for (int it = 0; it < 8; it++) {
        int sl = ms[it] >> 16;
        const float* xr = &xs[sl][ch0];
        float4 x0 = *(const float4*)xr;
        float4 x1 = *(const float4*)(xr + 4);
        uint4 tv = tvv[it];
        acc[0] += bflo(tv.x) * x0.x; acc[1] += bfhi(tv.x) * x0.y;
        acc[2] += bflo(tv.y) * x0.z; acc[3] += bfhi(tv.y) * x0.w;
        acc[4] += bflo(tv.z) * x1.x; acc[5] += bfhi(tv.z) * x1.y;
        acc[6] += bflo(tv.w) * x1.z; acc[7] += bfhi(tv.w) * x1.w;
      }
      #pragma unroll
      for (int j = 0; j < 8; j++) {
        acc[j] += __shfl_xor(acc[j], 16);
        acc[j] += __shfl_xor(acc[j], 32);
      }
      if (eg == 0) {
        short hv[8], lv[8];
        #pragma unroll
        for (int j = 0; j < 8; j++) {
          unsigned short hb = bf16_rne(acc[j]);
          hv[j] = (short)hb;
          lv[j] = (short)bf16_rne(acc[j] - bf16_to_f(hb));
        }
        *(short8_t*)&S1H[a2][ch0] = *(short8_t*)hv;
        *(short8_t*)&S1L[a2][ch0] = *(short8_t*)lv;
      }
    }
    __syncthreads();
    // ---- GEMM1: t = ssp(S1 @ cf_w2[l] + cf_b2[l]) -> S1 ----
    {
      short8_t ah[4], al_[4];
      load_afrags(S1H, S1L, rt, ln, quad, ah, al_);
      f32x4 acc[2];
      gemm2w(ah, al_, PW + (size_t)(2 * l) * 32768, nt0, lane, acc);
      __syncthreads();
      #pragma unroll
      for (int ct = 0; ct < 2; ct++) {
        int col = (nt0 + ct) * 16 + ln;
        float bb = cf_b2[l * H + col];
        #pragma unroll
        for (int reg = 0; reg < 4; reg++) {
          int row = rt * 16 + quad * 4 + reg;
          float v = ssp_f(acc[ct][reg] + bb);
          unsigned short hb = bf16_rne(v);
          S1H[row][col] = (short)hb;
          S1L[row][col] = (short)bf16_rne(v - bf16_to_f(hb));
        }
      }
    }
    __syncthreads();
    // ---- GEMM2: h += t @ int_w[l] + int_b[l] ----
    {
      short8_t ah[4], al_[4];
      load_afrags(S1H, S1L, rt, ln, quad, ah, al_);
      f32x4 acc[2];
      gemm2w(ah, al_, PW + (size_t)(2 * l + 1) * 32768, nt0, lane, acc);
      #pragma unroll
      for (int ct = 0; ct < 2; ct++) {
        int col = (nt0 + ct) * 16 + ln;
        float bb = int_b[l * H + col];
        #pragma unroll
        for (int reg = 0; reg < 4; reg++) {
          int row = rt * 16 + quad * 4 + reg;
          float hv = bf16_to_f((unsigned short)hH[row][col]) +
                     bf16_to_f((unsigned short)hL[row][col]);
          float v = acc[ct][reg] + bb + hv;
          unsigned short hb = bf16_rne(v);
          hH[row][col] = (short)hb;
          hL[row][col] = (short)bf16_rne(v - bf16_to_f(hb));
        }
      }
    }
    __syncthreads();
    // ---- GEMM3: xs = h @ cf_w1[l+1] ----
    if (l < NL - 1) {
      short8_t ah[4], al_[4];
      load_afrags(hH, hL, rt, ln, quad, ah, al_);
      f32x4 acc[2];
      gemm2w(ah, al_, PW + (size_t)(13 + l) * 32768, nt0, lane, acc);
      #pragma unroll
      for (int ct = 0; ct < 2; ct++)
        #pragma unroll
        for (int reg = 0; reg < 4; reg++)
          xs[rt * 16 + quad * 4 + reg][(nt0 + ct) * 16 + ln] = acc[ct][reg];
      __syncthreads();
    }
  }

  // ---- readout GEMM1: S1 = ssp(h @ out_w1 + out_b1) ----
  {
    short8_t ah[4], al_[4];
    load_afrags(hH, hL, rt, ln, quad, ah, al_);
    f32x4 acc[2];
    gemm2w(ah, al_, PW + (size_t)18 * 32768, nt0, lane, acc);
    __syncthreads();
    #pragma unroll
    for (int ct = 0; ct < 2; ct++) {
      int col = (nt0 + ct) * 16 + ln;
      float bb = out_b1[col];
      #pragma unroll
      for (int reg = 0; reg < 4; reg++) {
        int row = rt * 16 + quad * 4 + reg;
        float v = ssp_f(acc[ct][reg] + bb);
        unsigned short hb = bf16_rne(v);
        S1H[row][col] = (short)hb;
        S1L[row][col] = (short)bf16_rne(v - bf16_to_f(hb));
      }
    }
  }
  __syncthreads();
  // ---- readout GEMM2 + row-sum pool ----
  {
    short8_t ah[4], al_[4];
    load_afrags(S1H, S1L, rt, ln, quad, ah, al_);
    f32x4 acc[2];
    gemm2w(ah, al_, PW + (size_t)19 * 32768, nt0, lane, acc);
    #pragma unroll
    for (int ct = 0; ct < 2; ct++) {
      int col = (nt0 + ct) * 16 + ln;
      float s = acc[ct][0] + acc[ct][1] + acc[ct][2] + acc[ct][3];
      s += __shfl_xor(s, 16);
      s += __shfl_xor(s, 32);
      if (quad == 0) ps[rt][col] = s;
    }
  }
  __syncthreads();
  if (tid < 128) {
    float v = ps[0][tid] + ps[1][tid] + ps[2][tid] + ps[3][tid] + 64.f * out_b2[tid];
    __hip_atomic_store(&ce[conf * 128 + tid], v, __ATOMIC_RELAXED,
                       __HIP_MEMORY_SCOPE_AGENT);
  }
  __syncthreads();
  if (tid == 0) {
    __threadfence();
    int old = __hip_atomic_fetch_add(cnt, 1, __ATOMIC_ACQ_REL,
                                     __HIP_MEMORY_SCOPE_AGENT);
    is_last = (old == N_CONF - 1) ? 1 : 0;
  }
  __syncthreads();
  if (is_last) {
    __threadfence();
    float* mol = &xs[0][0];         // 64*128 floats (flat scratch)
    for (int t = tid; t < N_MOL * 128; t += 1024) {
      int m = t >> 7, c = t & 127;
      const float* bb = ce + (size_t)(m * 4) * 128;
      float s = __hip_atomic_load(&bb[c], __ATOMIC_RELAXED, __HIP_MEMORY_SCOPE_AGENT) +
                __hip_atomic_load(&bb[128 + c], __ATOMIC_RELAXED, __HIP_MEMORY_SCOPE_AGENT) +
                __hip_atomic_load(&bb[256 + c], __ATOMIC_RELAXED, __HIP_MEMORY_SCOPE_AGENT) +
                __hip_atomic_load(&bb[384 + c], __ATOMIC_RELAXED, __HIP_MEMORY_SCOPE_AGENT);
      mol[t] = s;
    }
    __syncthreads();
    float* q = (float*)&S1H[0][0];  // 64*64 floats (flat scratch)
    for (int t = tid; t < N_MOL * 64; t += 1024) {
      int m = t >> 6, j = t & 63;
      float qq = hb1[j];
      #pragma unroll 8
      for (int c = 0; c < H; c++) qq += mol[m * 128 + c] * hw1[c * 64 + j];
      q[t] = ssp_f(qq);
    }
    __syncthreads();
    if (tid < N_MOL) {
      float o = hb2[0];
      #pragma unroll 8
      for (int j = 0; j < 64; j++) o += q[tid * 64 + j] * hw2[j];
      outp[tid] = o;
    }
  }
}

extern "C" void kernel_launch(void* const* d_in, const int* in_sizes, int n_in,
                              void* d_out, int out_size, void* d_ws, size_t ws_size,
                              hipStream_t stream) {
  const int*   z       = (const int*)d_in[0];
  const float* pos     = (const float*)d_in[1];
  const int*   eidx    = (const int*)d_in[2];
  const float* emb     = (const float*)d_in[5];
  const float* mlp_w1  = (const float*)d_in[6];
  const float* mlp_b1  = (const float*)d_in[7];
  const float* mlp_w2  = (const float*)d_in[8];
  const float* mlp_b2  = (const float*)d_in[9];
  const float* cf_w1   = (const float*)d_in[10];
  const float* cf_w2   = (const float*)d_in[11];
  const float* cf_b2   = (const float*)d_in[12];
  const float* int_w   = (const float*)d_in[13];
  const float* int_b   = (const float*)d_in[14];
  const float* out_w1  = (const float*)d_in[15];
  const float* out_b1  = (const float*)d_in[16];
  const float* out_w2  = (const float*)d_in[17];
  const float* out_b2  = (const float*)d_in[18];
  const float* head_w1 = (const float*)d_in[19];
  const float* head_b1 = (const float*)d_in[20];
  const float* head_w2 = (const float*)d_in[21];
  const float* head_b2 = (const float*)d_in[22];

  char* ws = (char*)d_ws;
  float*          T   = (float*)ws;                             // 1,572,864 B
  unsigned short* Tb  = (unsigned short*)(ws + 1572864);        // 6,291,456 B
  short*          PW  = (short*)(ws + 1572864 + 6291456);       // 1,310,720 B
  float*          ce  = (float*)(ws + 9175040);                 //   131,072 B
  int*            cnt = (int*)(ws + 9306112);                   //         4 B

  hipMemsetAsync(cnt, 0, 4, stream);
  k_setup<<<1696, 256, 0, stream>>>(cf_w1, cf_w2, int_w, out_w1, out_w2, PW,
                                    mlp_w1, mlp_b1, mlp_w2, mlp_b2, T);
  k_up<<<(NL * TPB * H / 4) / 256, 256, 0, stream>>>(T, Tb);
  k_mega<<<N_CONF, 1024, 0, stream>>>(z, pos, eidx, emb, Tb, PW, cf_b2, int_b,
                                      out_b1, out_b2, ce,
                                      head_w1, head_b1, head_w2, head_b2,
                                      cnt, (float*)d_out);
}